// Round 1
// 397.196 us; speedup vs baseline: 1.0471x; 1.0471x over previous
//
#include <hip/hip_runtime.h>
#include <cstdint>
#include <cstddef>

// GCN: N=512, B=64, F=O=128, E=3, 2 layers. fp32 in memory, bf16 MFMA compute.
//
//   k_prep     : 8 blocks; weights -> wt bf16 [layer][4][o][f] (g<3: W[e]^T, 3: Wh^T)
//   k_support  : grid (8,64) = (n-tile 64, b); sup[e,b,o,n] = bf16(W^T X^T + bias),
//                tg[n,b,o] = sigmoid(X Wh + bh). LDS-staged, padded rows (manual).
//   k_convert  : pure streaming adj fp32 -> adjb bf16 (nontemporal reads; writes
//                cached so adjb stays L3-resident for k_agg L1).
//   k_agg      : grid (64,8) = (b, m-tile 64); out = relu(sum adjb.sup^T)*t + x*(1-t)
//                Double-buffered LDS + counted s_waitcnt vmcnt(6) + raw s_barrier:
//                next chunk's 6 gl_lds stay in flight across the barrier (T3/T4),
//                s_setprio around MFMA (T5). Grid (b, mt) so all 8 m-tiles of one b
//                share an XCD (flat%8 == b%8) -> sup panel is L2-hot.
// Layer-1 h lives in d_out; layer 2 in-place on d_out.

typedef __bf16 bf16x8 __attribute__((ext_vector_type(8)));
typedef float f32x4 __attribute__((ext_vector_type(4)));
typedef unsigned short u16x8 __attribute__((ext_vector_type(8)));

#define MFMA16(a, b, c) __builtin_amdgcn_mfma_f32_16x16x32_bf16((a), (b), (c), 0, 0, 0)

__device__ __forceinline__ unsigned short f2bf(float f) {  // RNE
  union { float f; unsigned int i; } v;
  v.f = f;
  return (unsigned short)((v.i + 0x7FFFu + ((v.i >> 16) & 1u)) >> 16);
}

// async global->LDS, 16B per lane; lds dest = wave-uniform base + lane*16
__device__ __forceinline__ void gl_lds16(const void* g, void* l) {
  __builtin_amdgcn_global_load_lds(
      (__attribute__((address_space(1))) void*)(g),
      (__attribute__((address_space(3))) void*)(l), 16, 0, 0);
}

// ---------------------------------------------------------------------------
// k_prep: 8 blocks; each transposes one 128x128 weight fp32 -> bf16 [o][f].
// ---------------------------------------------------------------------------
__global__ __launch_bounds__(256) void k_prep(
    const float* __restrict__ W1, const float* __restrict__ Wh1,
    const float* __restrict__ W2, const float* __restrict__ Wh2,
    unsigned short* __restrict__ wt) {
  __shared__ unsigned short T[128 * 136];
  const int tid = threadIdx.x;
  const int layer = blockIdx.x >> 2, g = blockIdx.x & 3;
  const float* src = (g < 3) ? ((layer ? W2 : W1) + g * 16384)
                             : (layer ? Wh2 : Wh1);
  unsigned short* dst = wt + layer * 65536 + g * 16384;
#pragma unroll
  for (int i = 0; i < 16; ++i) {
    int c = i * 256 + tid, f = c >> 5, p = (c & 31) * 4;
    float4 v = *(const float4*)(src + f * 128 + p);
    T[(p + 0) * 136 + f] = f2bf(v.x);
    T[(p + 1) * 136 + f] = f2bf(v.y);
    T[(p + 2) * 136 + f] = f2bf(v.z);
    T[(p + 3) * 136 + f] = f2bf(v.w);
  }
  __syncthreads();
#pragma unroll
  for (int i = 0; i < 8; ++i) {
    int c = i * 256 + tid, o = c >> 4, p = (c & 15) * 8;
    *(uint4*)(dst + o * 128 + p) = *(const uint4*)(&T[o * 136 + p]);
  }
}

// ---------------------------------------------------------------------------
// k_convert: adj fp32 [E,B,N,N] -> adjb bf16, pure streaming.
// 50331648 elements = 6291456 x 8; grid 2048x256 -> 12 iters/thread exact.
// ---------------------------------------------------------------------------
__global__ __launch_bounds__(256) void k_convert(
    const float* __restrict__ src, unsigned short* __restrict__ dst) {
  const long long n8 = 6291456LL;
  long long i = (long long)blockIdx.x * 256 + threadIdx.x;
  const long long stride = (long long)gridDim.x * 256;
#pragma unroll 2
  for (; i < n8; i += stride) {
    const f32x4* p = (const f32x4*)(src + i * 8);
    f32x4 v0 = __builtin_nontemporal_load(p);      // dead after this: keep out of L3
    f32x4 v1 = __builtin_nontemporal_load(p + 1);
    u16x8 u = { f2bf(v0[0]), f2bf(v0[1]), f2bf(v0[2]), f2bf(v0[3]),
                f2bf(v1[0]), f2bf(v1[1]), f2bf(v1[2]), f2bf(v1[3]) };
    *(u16x8*)(dst + i * 8) = u;                    // cached: wanted L3-hot for k_agg
  }
}

// ---------------------------------------------------------------------------
// k_support: grid (8,64) = (n-tile 64, b). 4 waves. LDS ~52KB.
// g<3 : D[o,n] = W[g]^T @ X^T -> sup bf16 (+bias)     (M=o 128, N=n 64)
// g==3: D[n,o] = X @ Wh       -> tg fp32 sigmoid      (M=n 64, O=o 128)
// ---------------------------------------------------------------------------
__global__ __launch_bounds__(256) void k_support(
    const float* __restrict__ x, const unsigned short* __restrict__ wt,
    const float* __restrict__ bias, const float* __restrict__ bh,
    unsigned short* __restrict__ sup, float* __restrict__ tg) {
  __shared__ __align__(16) unsigned short Xs[64 * 136];   // [n][f] bf16, padded
  __shared__ __align__(16) unsigned short Ws[128 * 136];  // [o][f] bf16, padded
  const int tid = threadIdx.x, lane = tid & 63, wv = tid >> 6;
  const int l15 = lane & 15, q = lane >> 4;
  const int b = blockIdx.y, n0 = blockIdx.x * 64;

  // stage Xs: 64 n-rows x 128 f (fp32 -> bf16)
#pragma unroll
  for (int is = 0; is < 8; ++is) {
    int flat = is * 256 + tid;  // 0..2047
    int row = flat >> 5, c4 = (flat & 31) * 4;
    float4 v = *(const float4*)(x + (size_t)(n0 + row) * 8192 + b * 128 + c4);
    ushort4 u = { f2bf(v.x), f2bf(v.y), f2bf(v.z), f2bf(v.w) };
    *(ushort4*)(&Xs[row * 136 + c4]) = u;
  }

  for (int g = 0; g < 4; ++g) {
    __syncthreads();  // Ws overwrite vs previous g's reads (also fences Xs at g=0)
#pragma unroll
    for (int is = 0; is < 8; ++is) {
      int flat = is * 256 + tid;  // 0..2047
      int row = flat >> 4, c8 = (flat & 15) * 8;
      *(uint4*)(&Ws[row * 136 + c8]) =
          *(const uint4*)(wt + g * 16384 + row * 128 + c8);
    }
    __syncthreads();

    if (g < 3) {
      f32x4 acc[4][2];
#pragma unroll
      for (int i = 0; i < 4; ++i)
#pragma unroll
        for (int j = 0; j < 2; ++j) acc[i][j] = (f32x4){0.f, 0.f, 0.f, 0.f};
#pragma unroll
      for (int kt = 0; kt < 4; ++kt) {
        int kf = kt * 32 + q * 8;
        bf16x8 a[4], bb[2];
#pragma unroll
        for (int mt = 0; mt < 4; ++mt)
          a[mt] = *(const bf16x8*)(&Ws[((wv >> 1) * 64 + mt * 16 + l15) * 136 + kf]);
#pragma unroll
        for (int nt = 0; nt < 2; ++nt)
          bb[nt] = *(const bf16x8*)(&Xs[((wv & 1) * 32 + nt * 16 + l15) * 136 + kf]);
#pragma unroll
        for (int mt = 0; mt < 4; ++mt)
#pragma unroll
          for (int nt = 0; nt < 2; ++nt)
            acc[mt][nt] = MFMA16(a[mt], bb[nt], acc[mt][nt]);
      }
      const size_t sb = (size_t)(g * 64 + b) * 65536;
#pragma unroll
      for (int mt = 0; mt < 4; ++mt) {
#pragma unroll
        for (int nt = 0; nt < 2; ++nt) {
          int nn = n0 + (wv & 1) * 32 + nt * 16 + l15;
#pragma unroll
          for (int r = 0; r < 4; ++r) {
            int o = (wv >> 1) * 64 + mt * 16 + q * 4 + r;
            float v = acc[mt][nt][r] + bias[g * 128 + o];
            sup[sb + (size_t)o * 512 + nn] = f2bf(v);
          }
        }
      }
    } else {
      f32x4 acc[2][4];
#pragma unroll
      for (int i = 0; i < 2; ++i)
#pragma unroll
        for (int j = 0; j < 4; ++j) acc[i][j] = (f32x4){0.f, 0.f, 0.f, 0.f};
#pragma unroll
      for (int kt = 0; kt < 4; ++kt) {
        int kf = kt * 32 + q * 8;
        bf16x8 a[2], bb[4];
#pragma unroll
        for (int mt = 0; mt < 2; ++mt)
          a[mt] = *(const bf16x8*)(&Xs[((wv >> 1) * 32 + mt * 16 + l15) * 136 + kf]);
#pragma unroll
        for (int nt = 0; nt < 4; ++nt)
          bb[nt] = *(const bf16x8*)(&Ws[((wv & 1) * 64 + nt * 16 + l15) * 136 + kf]);
#pragma unroll
        for (int mt = 0; mt < 2; ++mt)
#pragma unroll
          for (int nt = 0; nt < 4; ++nt)
            acc[mt][nt] = MFMA16(a[mt], bb[nt], acc[mt][nt]);
      }
#pragma unroll
      for (int mt = 0; mt < 2; ++mt) {
#pragma unroll
        for (int nt = 0; nt < 4; ++nt) {
          int o = (wv & 1) * 64 + nt * 16 + l15;
#pragma unroll
          for (int r = 0; r < 4; ++r) {
            int nn = n0 + (wv >> 1) * 32 + mt * 16 + q * 4 + r;
            float v = acc[mt][nt][r] + bh[o];
            tg[((size_t)nn * 64 + b) * 128 + o] = 1.f / (1.f + __expf(-v));
          }
        }
      }
    }
  }
}

// ---------------------------------------------------------------------------
// k_agg: grid (64,8) = (b, m-tile 64). Block tile 64m x 128o, K=3e*512n in 24
// chunks of 64. LDS: double-buffered As 2x8KB + Bs 2x16KB, XOR-swizzled 16B
// chunks. Counted vmcnt pipeline: chunk t+1's 6 gl_lds/wave issued before
// waiting vmcnt(6) for chunk t -> memory pipe never drains in the main loop.
// Waves: wm=wv>>1 (m 32-half), wn=wv&1 (o 64-half); acc 2x4 frags.
// ---------------------------------------------------------------------------
__global__ __launch_bounds__(256) void k_agg(
    const unsigned short* __restrict__ adjb, const unsigned short* __restrict__ sup,
    const float* __restrict__ tg, const float* __restrict__ x,
    float* __restrict__ dst) {
  __shared__ __align__(16) unsigned short As[2][64 * 64];    // [m][n64] swizzled
  __shared__ __align__(16) unsigned short Bs[2][128 * 64];   // [o][n64] swizzled
  const int tid = threadIdx.x, lane = tid & 63, wv = tid >> 6;
  const int l15 = lane & 15, q = lane >> 4;
  const int wm = wv >> 1, wn = wv & 1;
  const int b = blockIdx.x, m0 = blockIdx.y * 64;   // (b fast) -> same-b blocks share XCD
  const int srow = tid >> 3, sc = tid & 7;          // staging: row-in-32, 16B chunk

  f32x4 acc[2][4];
#pragma unroll
  for (int i = 0; i < 2; ++i)
#pragma unroll
    for (int j = 0; j < 4; ++j) acc[i][j] = (f32x4){0.f, 0.f, 0.f, 0.f};

  auto stage = [&](int ch, int buf) {
    const int e = ch >> 3, kt = ch & 7;
    const size_t arow0 = (size_t)(e * 64 + b) * 512 + m0;
    const size_t sbase = (size_t)(e * 64 + b) * 65536;
#pragma unroll
    for (int is = 0; is < 2; ++is) {
      int row = is * 32 + srow;
      int gc = sc ^ (row & 7);
      gl_lds16(adjb + (arow0 + row) * 512 + kt * 64 + gc * 8,
               &As[buf][is * 2048 + wv * 512]);
    }
#pragma unroll
    for (int is = 0; is < 4; ++is) {
      int row = is * 32 + srow;
      int gc = sc ^ (row & 7);
      gl_lds16(sup + sbase + (size_t)row * 512 + kt * 64 + gc * 8,
               &Bs[buf][is * 2048 + wv * 512]);
    }
  };

  stage(0, 0);  // prologue: 6 gl_lds in flight
  for (int ch = 0; ch < 24; ++ch) {
    const int buf = ch & 1;
    if (ch < 23) {
      stage(ch + 1, buf ^ 1);  // 12 outstanding
      asm volatile("s_waitcnt vmcnt(6)" ::: "memory");  // chunk ch landed, t+1 in flight
    } else {
      asm volatile("s_waitcnt vmcnt(0)" ::: "memory");  // epilogue chunk: full drain
    }
    __builtin_amdgcn_s_barrier();       // all waves' chunk-ch data visible in LDS
    asm volatile("" ::: "memory");      // no LDS read hoists above the barrier
    __builtin_amdgcn_s_setprio(1);
#pragma unroll
    for (int kh = 0; kh < 2; ++kh) {
      bf16x8 af[2], bfr[4];
#pragma unroll
      for (int mt = 0; mt < 2; ++mt) {
        int r = wm * 32 + mt * 16 + l15;
        int p = (kh * 4 + q) ^ (r & 7);
        af[mt] = *(const bf16x8*)(&As[buf][r * 64 + p * 8]);
      }
#pragma unroll
      for (int ot = 0; ot < 4; ++ot) {
        int r = wn * 64 + ot * 16 + l15;
        int p = (kh * 4 + q) ^ (r & 7);
        bfr[ot] = *(const bf16x8*)(&Bs[buf][r * 64 + p * 8]);
      }
#pragma unroll
      for (int mt = 0; mt < 2; ++mt)
#pragma unroll
        for (int ot = 0; ot < 4; ++ot)
          acc[mt][ot] = MFMA16(af[mt], bfr[ot], acc[mt][ot]);
    }
    __builtin_amdgcn_s_setprio(0);
    asm volatile("" ::: "memory");      // LDS reads stay above the barrier
    __builtin_amdgcn_s_barrier();       // all reads of buf done before it is restaged
  }

  // Epilogue: relu + highway. C row=m (q*4+r), col=o (l15).
#pragma unroll
  for (int mt = 0; mt < 2; ++mt) {
#pragma unroll
    for (int ot = 0; ot < 4; ++ot) {
#pragma unroll
      for (int r = 0; r < 4; ++r) {
        int m = m0 + wm * 32 + mt * 16 + q * 4 + r;
        int o = wn * 64 + ot * 16 + l15;
        size_t ridx = (size_t)(m * 64 + b) * 128 + o;
        float agg = acc[mt][ot][r];
        agg = agg > 0.f ? agg : 0.f;
        float tv = tg[ridx];
        float xv = x[ridx];
        dst[ridx] = fmaf(agg, tv, xv * (1.f - tv));
      }
    }
  }
}

// ---------------------------------------------------------------------------
extern "C" void kernel_launch(void* const* d_in, const int* in_sizes, int n_in,
                              void* d_out, int out_size, void* d_ws, size_t ws_size,
                              hipStream_t stream) {
  const float* x   = (const float*)d_in[0];
  const float* adj = (const float*)d_in[1];
  const float* W1  = (const float*)d_in[2];
  const float* b1  = (const float*)d_in[3];
  const float* Wh1 = (const float*)d_in[4];
  const float* bh1 = (const float*)d_in[5];
  const float* W2  = (const float*)d_in[6];
  const float* b2  = (const float*)d_in[7];
  const float* Wh2 = (const float*)d_in[8];
  const float* bh2 = (const float*)d_in[9];
  float* out = (float*)d_out;

  char* ws = (char*)d_ws;
  unsigned short* adjb = (unsigned short*)ws;                // 100,663,296 B
  unsigned short* sup  = (unsigned short*)(ws + 100663296);  //  25,165,824 B
  float*          tg   = (float*)(ws + 125829120);           //  16,777,216 B
  unsigned short* wt   = (unsigned short*)(ws + 142606336);  //     262,144 B

  dim3 blk(256);

  k_prep<<<dim3(8), blk, 0, stream>>>(W1, Wh1, W2, Wh2, wt);

  // Layer 1 (h -> d_out). Convert adj right before agg1 so adjb is L3-hot.
  k_support<<<dim3(8, 64), blk, 0, stream>>>(x, wt, b1, bh1, sup, tg);
  k_convert<<<dim3(2048), blk, 0, stream>>>(adj, adjb);
  k_agg<<<dim3(64, 8), blk, 0, stream>>>(adjb, sup, tg, x, out);

  // Layer 2 (in-place on d_out)
  k_support<<<dim3(8, 64), blk, 0, stream>>>(out, wt + 65536, b2, bh2, sup, tg);
  k_agg<<<dim3(64, 8), blk, 0, stream>>>(adjb, sup, tg, out, out);
}